// Round 1
// 113.558 us; speedup vs baseline: 1.0057x; 1.0057x over previous
//
#include <hip/hip_runtime.h>
#include <math.h>

// total = main_ce + 0.05*rep + 0.2*chord_ce + 0.1*scale_bce
// rep_loss is data-independent: 0.5 * sum_pos min(pos,8) / (S*VOCAB)
// (one-hot rows sum to 1 since ids are always in [0,VOCAB)).
//
// Two-kernel structure is deliberate (measured): fusing the finalize into the
// leaf kernel via last-block + __threadfence() costs ~77 ns/block of L2
// writeback on multi-XCD gfx950 (R5: 799 us kernel). The kernel-launch
// boundary IS the cheap device-scope fence.
//
// R(this): main CE restructured to ONE ROW PER WAVE (was one row per
// 256-thread block): 8x16B loads in flight per lane (was 2), zero barriers
// in the row hot path (was 2 + 2 LDS round-trips), 4-row pre-reduction per
// block so finalize reads 16KB of main partials instead of 64KB.

#define VOCAB 2048
#define CHORDV 60

// native vector type: required by __builtin_nontemporal_load (HIP float4 is a struct)
typedef float vf4 __attribute__((ext_vector_type(4)));

__device__ __forceinline__ float waveRedMax(float v) {
#pragma unroll
    for (int off = 32; off > 0; off >>= 1)
        v = fmaxf(v, __shfl_xor(v, off, 64));
    return v;
}

__device__ __forceinline__ float waveRedSum(float v) {
#pragma unroll
    for (int off = 32; off > 0; off >>= 1)
        v += __shfl_xor(v, off, 64);
    return v;
}

__device__ __forceinline__ float bce1(float x, float z) {
    // numerically stable BCE-with-logits; __expf/__logf -> v_exp_f32/v_log_f32
    return fmaxf(x, 0.0f) - x * z + __logf(1.0f + __expf(-fabsf(x)));
}

// ---------------- fused leaf kernel ----------------
// blocks [0, mainBlocks): main CE, 4 rows of 2048 per block (1 row/wave), pre-reduced
// blocks [mainBlocks, +chordBlocks): chord CE, 4 rows of 60 per block (1/wave), pre-reduced
// blocks [mainBlocks+chordBlocks, ...): scale BCE, 1024 elems per block
__global__ __launch_bounds__(256) void fused_leaf_kernel(
    const float* __restrict__ logits, const int* __restrict__ tgt,
    const float* __restrict__ chordL, const int* __restrict__ chordT,
    const float* __restrict__ sx, const float* __restrict__ sz,
    float2* __restrict__ mainNV, float2* __restrict__ chordNV,
    float* __restrict__ scaleP, int BS, int mainBlocks, int chordBlocks, int n4) {
    const int bid = blockIdx.x;
    const int tid = threadIdx.x;
    const int lane = tid & 63;
    const int wave = tid >> 6;

    __shared__ float2 sh2[4];
    __shared__ float red[4];

    if (bid < mainBlocks) {
        // ---- main CE: one 2048-logit row per wave ----
        const int row = bid * 4 + wave;
        float2 nv = make_float2(0.0f, 0.0f);
        if (row < BS) {  // uniform per wave -> no intra-wave divergence
            const int t = tgt[row];  // scalar load, issued before the row stream
            const vf4* p4 = (const vf4*)(logits + (size_t)row * VOCAB);

            // 32 floats/lane as 8 x 16B nontemporal loads, all independent ->
            // 8 outstanding VMEM ops/lane. Read-once stream: bypass caches.
            vf4 v[8];
#pragma unroll
            for (int k = 0; k < 8; ++k)
                v[k] = __builtin_nontemporal_load(p4 + lane + 64 * k);

            float m = -INFINITY;
#pragma unroll
            for (int k = 0; k < 8; ++k)
                m = fmaxf(m, fmaxf(fmaxf(v[k].x, v[k].y), fmaxf(v[k].z, v[k].w)));
            m = waveRedMax(m);

            float s = 0.0f;
#pragma unroll
            for (int k = 0; k < 8; ++k)
                s += __expf(v[k].x - m) + __expf(v[k].y - m) +
                     __expf(v[k].z - m) + __expf(v[k].w - m);
            s = waveRedSum(s);

            const bool valid = (t >= 0) && (t < VOCAB);
            if (valid) {
                // target logit from the owning lane's registers (no reload, no LDS)
                const int vi = t >> 2;        // vf4 index 0..511 (uniform)
                const int owner = vi & 63;    // owning lane
                const int chunk = vi >> 6;    // which of the 8 per-lane vf4s
                const int comp = t & 3;
                float cand = 0.0f;
#pragma unroll
                for (int k = 0; k < 8; ++k) {  // compile-time indices only (no scratch)
                    if (chunk == k) {
                        const float lo = (comp & 1) ? v[k].y : v[k].x;
                        const float hi = (comp & 1) ? v[k].w : v[k].z;
                        cand = (comp & 2) ? hi : lo;
                    }
                }
                const float xt = __shfl(cand, owner, 64);
                nv.x = -(xt - m - __logf(s));
                nv.y = 1.0f;
            }
        }
        // 4-row pre-reduction: one float2 per block (finalize reads 4x less)
        if (lane == 0) sh2[wave] = nv;
        __syncthreads();
        if (tid == 0)
            mainNV[bid] = make_float2(sh2[0].x + sh2[1].x + sh2[2].x + sh2[3].x,
                                      sh2[0].y + sh2[1].y + sh2[2].y + sh2[3].y);
    } else if (bid < mainBlocks + chordBlocks) {
        // ---- chord CE: 4 rows, one per wave, pre-reduced to one float2 ----
        const int cb = bid - mainBlocks;
        const int row = cb * 4 + wave;
        float2 nv = make_float2(0.0f, 0.0f);
        if (row < BS) {
            const float* p = chordL + (size_t)row * CHORDV;
            const int t = chordT[row];
            float x = (lane < CHORDV) ? __builtin_nontemporal_load(p + lane) : -INFINITY;
            float m = waveRedMax(x);
            float e = (lane < CHORDV) ? __expf(x - m) : 0.0f;
            float s = waveRedSum(e);
            if (t != -1000000000) {  // ignore_index = -(10**9), never hit here
                const int tt = (t >= 0 && t < CHORDV) ? t : 0;
                const float xt = __shfl(x, tt, 64);  // target logit from owning lane
                nv.x = -(xt - m - __logf(s));
                nv.y = 1.0f;
            }
        }
        if (lane == 0) sh2[wave] = nv;
        __syncthreads();
        if (tid == 0)
            chordNV[cb] = make_float2(sh2[0].x + sh2[1].x + sh2[2].x + sh2[3].x,
                                      sh2[0].y + sh2[1].y + sh2[2].y + sh2[3].y);
    } else {
        // ---- scale BCE ----
        const int sb = bid - mainBlocks - chordBlocks;
        const int i = sb * 256 + tid;
        float s = 0.0f;
        if (i < n4) {
            vf4 xv = __builtin_nontemporal_load(((const vf4*)sx) + i);
            vf4 zv = __builtin_nontemporal_load(((const vf4*)sz) + i);
            s = bce1(xv.x, zv.x) + bce1(xv.y, zv.y) + bce1(xv.z, zv.z) + bce1(xv.w, zv.w);
        }
        float wsum = waveRedSum(s);
        if (lane == 0) red[wave] = wsum;
        __syncthreads();
        if (tid == 0) scaleP[sb] = red[0] + red[1] + red[2] + red[3];
    }
}

// ---------------- finalize: 1 block x 1024 threads ----------------
__device__ __forceinline__ float blockSum1024(float v, float* red16) {
    const int lane = threadIdx.x & 63;
    const int wave = threadIdx.x >> 6;
    float w = waveRedSum(v);
    __syncthreads();  // guard reuse across calls
    if (lane == 0) red16[wave] = w;
    __syncthreads();
    float r = 0.0f;
#pragma unroll
    for (int k = 0; k < 16; ++k) r += red16[k];  // LDS broadcast, conflict-free
    return r;
}

__global__ __launch_bounds__(1024) void finalize_kernel(
    const float2* __restrict__ mainNV, const float2* __restrict__ chordNV,
    const float* __restrict__ scaleP, int mainBlocks, int chordBlocks, int nScaleBlocks,
    int S, int scaleN, float* __restrict__ out) {
    const int tid = threadIdx.x;
    float sm = 0.f, svm = 0.f, sc = 0.f, svc = 0.f, ss = 0.f;

    const float4* m4 = (const float4*)mainNV;  // (nll,valid) pairs, float4 = 2 partials
    for (int i = tid; i < mainBlocks / 2; i += 1024) {
        float4 v = m4[i];
        sm += v.x + v.z;
        svm += v.y + v.w;
    }
    if ((mainBlocks & 1) && tid == 0) { float2 v = mainNV[mainBlocks - 1]; sm += v.x; svm += v.y; }

    const float4* c4 = (const float4*)chordNV;
    for (int i = tid; i < chordBlocks / 2; i += 1024) {
        float4 v = c4[i];
        sc += v.x + v.z;
        svc += v.y + v.w;
    }
    if ((chordBlocks & 1) && tid == 0) { float2 v = chordNV[chordBlocks - 1]; sc += v.x; svc += v.y; }

    for (int i = tid; i < nScaleBlocks; i += 1024) ss += scaleP[i];

    __shared__ float red16[16];
    sm  = blockSum1024(sm,  red16);
    svm = blockSum1024(svm, red16);
    sc  = blockSum1024(sc,  red16);
    svc = blockSum1024(svc, red16);
    ss  = blockSum1024(ss,  red16);

    if (tid == 0) {
        const float main_loss  = sm / fmaxf(svm, 1.0f);
        const float chord_loss = sc / fmaxf(svc, 1.0f);
        const float scale_loss = ss / (float)scaleN;
        // rep_loss: data-independent constant (header comment)
        double wsum = (S >= 8) ? (28.0 + 8.0 * (double)(S - 8))
                               : ((double)S * (double)(S - 1) * 0.5);
        const float rep_loss = (float)(0.5 * wsum / ((double)S * (double)VOCAB));
        out[0] = main_loss + 0.05f * rep_loss + 0.2f * chord_loss + 0.1f * scale_loss;
    }
}

extern "C" void kernel_launch(void* const* d_in, const int* in_sizes, int n_in,
                              void* d_out, int out_size, void* d_ws, size_t ws_size,
                              hipStream_t stream) {
    const float* logits        = (const float*)d_in[0];  // [B,S,2048]
    const float* chord_logits  = (const float*)d_in[1];  // [B,S,60]
    const float* scale_logits  = (const float*)d_in[2];  // [B,S,12]
    const float* scale_targets = (const float*)d_in[3];  // [B,S,12]
    const int*   target_ids    = (const int*)d_in[4];    // [B,S]
    // d_in[5] = key_ids [B] — unused by the reference
    const int*   chord_targets = (const int*)d_in[6];    // [B,S]

    const int BS = in_sizes[4];       // B*S = 8192
    const int B  = in_sizes[5];
    const int S  = BS / B;
    const int scaleN = in_sizes[2];   // B*S*12 (divisible by 4)
    const int n4 = scaleN / 4;
    const int nScaleBlocks = (n4 + 255) / 256;
    const int mainBlocks  = (BS + 3) / 4;  // 4 rows per block (1 per wave)
    const int chordBlocks = (BS + 3) / 4;

    // ws layout (all written every call before being read — poison-safe):
    // [0, mainBlocks) float2 main (nll,valid) | then chordBlocks float2 chord
    // then nScaleBlocks floats of scale partials
    float2* mainNV  = (float2*)d_ws;
    float2* chordNV = mainNV + mainBlocks;
    float*  scaleP  = (float*)(chordNV + chordBlocks);

    const int totalBlocks = mainBlocks + chordBlocks + nScaleBlocks;
    fused_leaf_kernel<<<totalBlocks, 256, 0, stream>>>(
        logits, target_ids, chord_logits, chord_targets,
        scale_logits, scale_targets, mainNV, chordNV, scaleP,
        BS, mainBlocks, chordBlocks, n4);
    finalize_kernel<<<1, 1024, 0, stream>>>(mainNV, chordNV, scaleP,
                                            mainBlocks, chordBlocks, nScaleBlocks,
                                            S, scaleN, (float*)d_out);
}